// Round 9
// baseline (229.609 us; speedup 1.0000x reference)
//
#include <hip/hip_runtime.h>
#include <hip/hip_bf16.h>

// CausalAttention: B=4, S=2048, d=1024, single head, causal. fp32 I/O, bf16 MFMA inside.
//
// R17: fold x->bf16 conversion into QKV's A-staging (deletes cvt_f32_bf16, 100 MB
//      of pure movement, ~18-20 us, and the Xb buffer).
//      MODE 3 A-path: reg-stage fp32 x -> 2x float4 coalesced loads (the 8 swizzled
//      chunks of each 8-lane group cover a contiguous 256B row segment), 8 bf16 casts,
//      ds_write_b128 to the SAME swizzled LDS slot gload_lds used
//      (ldsA + j*512 + lane*8 == implicit lane*16B dest -- derived, layout identical).
//      B-path keeps global_load_lds and is issued first so it flies during the cvt.
//      __syncthreads ledger unchanged (drains vmcnt+lgkm for both paths).
//      Numerics: identical bf16 rounding -> absmax bit-identical.
//      R16 recap (verified): V written transposed in QKV epilogue (L2 write-merge,
//      zero cost); rowsum via ones-MFMA in PV; 544-tile tri grid for scores;
//      panel-pinned PV map (R14's 78 MB FETCH -> compulsory).
//
// Pipeline (4 dispatches):
//   1) Wq/Wk/Wv fp32 -> bf16 transposed, stacked Wt [3072][1024]
//   2) {Q,K,Vt} = x * Wt^T       (MODE 3, 128^2, grid 24x64; A staged from fp32 x)
//   3) E = masked-exp(Q*K^T/32)  (MODE 1, 128^2, flat tri grid 544; no rowsum)
//   4) out = (E*V) / (E*ones)    (MODE 2, 128^2, panel-pinned 512; rowsum via MFMA)

typedef __bf16 bf16_t;
typedef __bf16 bf16x8 __attribute__((ext_vector_type(8)));
typedef float f32x4 __attribute__((ext_vector_type(4)));

__device__ __forceinline__ void load_lds16(const bf16_t* g, bf16_t* l) {
  __builtin_amdgcn_global_load_lds(
      (__attribute__((address_space(1))) void*)(void*)g,
      (__attribute__((address_space(3))) void*)l,
      16, 0, 0);
}

// C[m][n] = sum_k A[m][k]*B[n][k]  (B:[N][K] row-major bf16)
// MODE: 1 scores: A bf16; flat triangular grid, epilogue mask+exp (no rowsum)
//       2 pv: A bf16; panel-pinned grid, K clamped, rowsum via ones-MFMA, epilogue 1/rs
//       3 qkv: A = fp32 x, converted during staging; V-third written transposed
// LDS swizzle: 16B chunk position p of row r holds global chunk p ^ (r&7);
// fragment reads hit all 32 banks 2-way (free, m136). Conflicts measured 0 (R5-R16).
template <int BMv, int BNv, int NW, int MODE, typename OT>
__global__ __launch_bounds__(NW * 64)
void gemm_nt_bf16(const bf16_t* __restrict__ A, const float* __restrict__ AF,
                  const bf16_t* __restrict__ B,
                  OT* __restrict__ C0, OT* __restrict__ C1, OT* __restrict__ C2,
                  int M, int K, int ldc,
                  long strideA, long strideB, long strideC)
{
  constexpr int MW = BMv / 64;       // wave grid: MW x (NW/MW)
  constexpr int RA = BMv / NW;       // rows staged per wave (A)
  constexpr int RB = BNv / NW;       // rows staged per wave (B)

  int bx, by, bz;
  if constexpr (MODE == 1) {
    // Flat XCD-balanced lower-triangle enumeration (S=2048, 128-tiles, 16 panels/batch).
    // XCD x (= blockIdx.x & 7, m09 round-robin) owns panels {x, 15-x} of every batch:
    // weight (x+1) + (16-x) = 17 tiles per batch -> 68 per XCD, exact balance.
    const int f = blockIdx.x;          // 544 blocks
    const int x = f & 7;
    const int j = f >> 3;              // [0, 68)
    bz = j / 17;
    const int r = j % 17;
    by = (r <= x) ? x : 15 - x;
    bx = (r <= x) ? r : r - (x + 1);
  } else if constexpr (MODE == 2) {
    // PV panel-pinned flat grid: 512 blocks. XCD = f&7 owns 8 E row-panels
    // (4 heavy-first pairs; (16-pr)+(pr+1)=17 -> 68 K-units per XCD exactly).
    // bx fastest: the 8 col-blocks of a panel are consecutive ON ONE XCD -> A-panel
    // fetched once, ~2.2 MB/XCD in L2 (R14: 78 MB FETCH with the un-pinned map).
    const int f  = blockIdx.x;
    const int xcd = f & 7;
    const int i  = f >> 3;             // [0,64) within XCD
    bx = i & 7;
    const int p  = i >> 3;             // [0,8) panel slot
    const int j  = p & 3;              // pair index
    const int heavy = (p < 4);         // heavy panels first
    const int g  = xcd * 4 + j;        // [0,32) global (bz,pr) pair
    bz = g >> 3;
    const int pr = g & 7;
    by = heavy ? (15 - pr) : pr;
  } else {
    // XCD-aware remap: pin all x-blocks of an A-panel (y,z) to one XCD.
    // Requires (gridDim.y*gridDim.z) % 8 == 0 -- true here (64).
    const int gx = gridDim.x, gy = gridDim.y;
    const int NP = gy * gridDim.z;
    const int P  = NP >> 3;                         // panels per XCD
    const int flat = blockIdx.x + gx * (blockIdx.y + gy * blockIdx.z);
    const int xcd  = flat & 7;
    const int i    = flat >> 3;
    const int pan  = xcd * P + (i % P);
    bx = i / P;
    by = pan % gy;
    bz = pan / gy;
  }

  const int rowBase = by * BMv;
  const int colBase = bx * BNv;

  __shared__ __align__(16) bf16_t sA[BMv * 64];
  __shared__ __align__(16) bf16_t sB[BNv * 64];

  A += (size_t)bz * strideA;
  B += (size_t)bz * strideB;

  const int tid  = threadIdx.x;
  const int wave = tid >> 6;
  const int lane = tid & 63;
  const int quad = lane >> 4;
  const int ln16 = lane & 15;

  const int wm = (wave % MW) * 64;
  const int wn = (wave / MW) * 64;

  const int rA = lane >> 3;                       // 0..7 row-in-group
  const int sColOff = ((lane & 7) ^ rA) * 8;      // swizzled chunk offset (elems)
  const bf16_t* pA = A + (size_t)(rowBase + wave * RA + rA) * K + sColOff;
  const float*  pAf = AF + (size_t)(rowBase + wave * RA + rA) * K + sColOff;
  const bf16_t* pB = B + (size_t)(colBase + wave * RB + rA) * K + sColOff;
  bf16_t* ldsA = sA + wave * RA * 64;
  bf16_t* ldsB = sB + wave * RB * 64;

  f32x4 acc[4][4] = {};
  f32x4 acc_rs[4] = {};                           // MODE 2: per-row E sums (ones-MFMA)
  bf16x8 ones;
#pragma unroll
  for (int i = 0; i < 8; i++) ones[i] = (bf16_t)1.0f;

  const int Kend = (MODE == 2) ? (K < rowBase + BMv ? K : rowBase + BMv) : K;

  for (int k0 = 0; k0 < Kend; k0 += 64) {
    // B first: its gload_lds flies while the A-path converts (MODE 3).
#pragma unroll
    for (int j = 0; j < RB / 8; j++)
      load_lds16(pB + k0 + (size_t)(8 * j) * K, ldsB + j * 512);
    if constexpr (MODE == 3) {
      // A from fp32 x: 2x float4 (32B/lane, coalesced: each 8-lane group's swizzled
      // chunks cover one contiguous 256B row segment), cvt, ds_write_b128 to the
      // exact slot gload_lds would fill (ldsA + j*512 + lane*8 elems = lane*16B).
#pragma unroll
      for (int j = 0; j < RA / 8; j++) {
        const float* src = pAf + k0 + (size_t)(8 * j) * K;
        const float4 u0 = *(const float4*)src;
        const float4 u1 = *(const float4*)(src + 4);
        bf16x8 w;
        w[0] = (bf16_t)u0.x; w[1] = (bf16_t)u0.y; w[2] = (bf16_t)u0.z; w[3] = (bf16_t)u0.w;
        w[4] = (bf16_t)u1.x; w[5] = (bf16_t)u1.y; w[6] = (bf16_t)u1.z; w[7] = (bf16_t)u1.w;
        *(bf16x8*)(ldsA + j * 512 + lane * 8) = w;
      }
    } else {
#pragma unroll
      for (int j = 0; j < RA / 8; j++)
        load_lds16(pA + k0 + (size_t)(8 * j) * K, ldsA + j * 512);
    }
    __syncthreads();   // drains vmcnt + lgkmcnt for all waves

#pragma unroll
    for (int kk = 0; kk < 2; kk++) {
      bf16x8 af[4], bfr[4];
#pragma unroll
      for (int mt = 0; mt < 4; mt++) {
        const int row = wm + mt * 16 + ln16;
        af[mt] = *(const bf16x8*)(sA + row * 64 + (((kk * 4 + quad) ^ (row & 7)) * 8));
      }
#pragma unroll
      for (int nt = 0; nt < 4; nt++) {
        const int row = wn + nt * 16 + ln16;
        bfr[nt] = *(const bf16x8*)(sB + row * 64 + (((kk * 4 + quad) ^ (row & 7)) * 8));
      }
#pragma unroll
      for (int mt = 0; mt < 4; mt++) {
#pragma unroll
        for (int nt = 0; nt < 4; nt++)
          acc[mt][nt] = __builtin_amdgcn_mfma_f32_16x16x32_bf16(af[mt], bfr[nt], acc[mt][nt], 0, 0, 0);
        if constexpr (MODE == 2)
          acc_rs[mt] = __builtin_amdgcn_mfma_f32_16x16x32_bf16(af[mt], ones, acc_rs[mt], 0, 0, 0);
      }
    }
    __syncthreads();
  }

  // epilogue: C/D layout col = lane&15, row = quad*4 + r  [measured m89/m91]
  if constexpr (MODE == 3) {
    const int which = colBase >> 10;               // 128-col tiles never span matrices
    const int cb = colBase & 1023;
    if (which == 2) {
      // V-third: write transposed into Vt[b][e][s]  (b=row>>11, e=col, s=row&2047).
      // Each block covers 128 contiguous s per e-row -> 64B lines fully written
      // within one block/XCD -> L2 write-merge keeps HBM traffic at 33.5 MB.
#pragma unroll
      for (int mt = 0; mt < 4; mt++) {
#pragma unroll
        for (int r = 0; r < 4; r++) {
          const int row = rowBase + wm + mt * 16 + quad * 4 + r;
          const size_t vb = (size_t)(row >> 11) * (1024 * 2048) + (row & 2047);
#pragma unroll
          for (int nt = 0; nt < 4; nt++) {
            const int col = cb + wn + nt * 16 + ln16;
            C2[vb + (size_t)col * 2048] = (OT)acc[mt][nt][r];
          }
        }
      }
    } else {
      OT* Cw = which ? C1 : C0;
#pragma unroll
      for (int mt = 0; mt < 4; mt++) {
#pragma unroll
        for (int r = 0; r < 4; r++) {
          const int row = rowBase + wm + mt * 16 + quad * 4 + r;
#pragma unroll
          for (int nt = 0; nt < 4; nt++) {
            const int col = cb + wn + nt * 16 + ln16;
            Cw[(size_t)row * ldc + col] = (OT)acc[mt][nt][r];
          }
        }
      }
    }
    return;
  }

  OT* Cw = C0 + (size_t)bz * strideC;
#pragma unroll
  for (int mt = 0; mt < 4; mt++) {
#pragma unroll
    for (int r = 0; r < 4; r++) {
      const int row = rowBase + wm + mt * 16 + quad * 4 + r;
      const float rinv = (MODE == 2) ? 1.0f / acc_rs[mt][r] : 1.0f;
#pragma unroll
      for (int nt = 0; nt < 4; nt++) {
        const int col = colBase + wn + nt * 16 + ln16;
        float v = acc[mt][nt][r];
        if constexpr (MODE == 1) {
          v = (col <= row) ? __expf(v * 0.03125f) : 0.0f;   // s/sqrt(1024)
        } else {
          v *= rinv;
        }
        Cw[(size_t)row * ldc + col] = (OT)v;
      }
    }
  }
}

// three fp32 [D][D] -> bf16 transposed, stacked [3D][D]; z selects source
__global__ __launch_bounds__(256)
void transpose_cvt3(const float* __restrict__ w0, const float* __restrict__ w1,
                    const float* __restrict__ w2, bf16_t* __restrict__ out, int D)
{
  const float* in = (blockIdx.z == 0) ? w0 : (blockIdx.z == 1) ? w1 : w2;
  bf16_t* o = out + (size_t)blockIdx.z * D * D;
  __shared__ float tile[32][33];
  const int c0 = blockIdx.x * 32, r0 = blockIdx.y * 32;
  const int tx = threadIdx.x, ty = threadIdx.y;  // (32, 8)
#pragma unroll
  for (int i = 0; i < 32; i += 8)
    tile[ty + i][tx] = in[(size_t)(r0 + ty + i) * D + (c0 + tx)];
  __syncthreads();
#pragma unroll
  for (int i = 0; i < 32; i += 8)
    o[(size_t)(c0 + ty + i) * D + (r0 + tx)] = (bf16_t)tile[tx][ty + i];
}

extern "C" void kernel_launch(void* const* d_in, const int* in_sizes, int n_in,
                              void* d_out, int out_size, void* d_ws, size_t ws_size,
                              hipStream_t stream) {
  const float* x  = (const float*)d_in[0];
  const float* Wq = (const float*)d_in[1];
  const float* Wk = (const float*)d_in[2];
  const float* Wv = (const float*)d_in[3];
  float* out = (float*)d_out;

  const int Bb = 4, S = 2048, D = 1024;
  const int M = Bb * S;  // 8192

  // ws (bf16 elems): Q | K | Vt | Wt(3*D*D) | Sc (Bb*S*S). No Xb, no rowsum.
  bf16_t* ws = (bf16_t*)d_ws;
  bf16_t* Q   = ws;
  bf16_t* Kp  = Q  + (size_t)M * D;
  bf16_t* Vt  = Kp + (size_t)M * D;
  bf16_t* Wt  = Vt + (size_t)M * D;          // [3072][1024] stacked
  bf16_t* Sc  = Wt + 3 * (size_t)D * D;

  const dim3 tb(32, 8);

  // 1) W fp32 -> bf16 transposed, stacked
  transpose_cvt3<<<dim3(D / 32, D / 32, 3), tb, 0, stream>>>(Wq, Wk, Wv, Wt, D);

  // 2) fused projections: {Q,K,Vt} = x * Wt^T  (A staged from fp32 x directly)
  gemm_nt_bf16<128, 128, 4, 3, bf16_t><<<dim3(3 * D / 128, M / 128, 1), dim3(256), 0, stream>>>(
      nullptr, x, Wt, Q, Kp, Vt, M, D, D, 0, 0, 0);

  // 3) E = masked-exp(Q*K^T/32)  (flat triangular grid: 544 tiles, 68/XCD exact)
  gemm_nt_bf16<128, 128, 4, 1, bf16_t><<<dim3(544, 1, 1), dim3(256), 0, stream>>>(
      Q, nullptr, Kp, Sc, Sc, Sc, S, D, S, (long)S * D, (long)S * D, (long)S * S);

  // 4) out = (E*V) / (E*ones)  (panel-pinned flat grid: 512 blocks, 68 K-units/XCD)
  gemm_nt_bf16<128, 128, 4, 2, float><<<dim3(512, 1, 1), dim3(256), 0, stream>>>(
      Sc, nullptr, Vt, out, out, out, S, S, D, (long)S * S, (long)D * S, (long)S * D);
}

// Round 10
// 224.403 us; speedup vs baseline: 1.0232x; 1.0232x over previous
//
#include <hip/hip_runtime.h>
#include <hip/hip_bf16.h>

// CausalAttention: B=4, S=2048, d=1024, single head, causal. fp32 I/O, bf16 MFMA inside.
//
// R18: revert R17 (reg-staging the A-path from fp32 x cost QKV +17 us > the 18 us cvt
//      dispatch it deleted -- m151's reg-staging penalty, exposed fully at the
//      2-barrier drain; staging work in-loop is serial, a separate memory-bound
//      dispatch streams at full HBM rate). Restore the R16 champion (223.8 us).
//      New: merge transpose_cvt3 + cvt_f32_bf16 into ONE `prep` dispatch
//      (flat 7168-block grid: 3072 W-transpose blocks + 4096 x-cvt blocks; disjoint
//      outputs, different resources -> overlap, one fewer launch gap). 4 dispatches.
//      R16 recap (all verified): V written transposed in QKV epilogue (L2 write-merge,
//      zero cost); rowsum via ones-MFMA in PV; 544-tile tri grid for scores;
//      panel-pinned PV map (R14's 78 MB FETCH -> compulsory).
//
// Pipeline (4 dispatches):
//   1) prep: Wt[3072][1024] = {Wq,Wk,Wv}^T in bf16  ||  Xb = bf16(x)
//   2) {Q,K,Vt} = Xb * Wt^T      (MODE 3, 128^2, grid 24x64; V written transposed)
//   3) E = masked-exp(Q*K^T/32)  (MODE 1, 128^2, flat tri grid 544; no rowsum)
//   4) out = (E*V) / (E*ones)    (MODE 2, 128^2, panel-pinned 512; rowsum via MFMA)

typedef __bf16 bf16_t;
typedef __bf16 bf16x8 __attribute__((ext_vector_type(8)));
typedef float f32x4 __attribute__((ext_vector_type(4)));

__device__ __forceinline__ void load_lds16(const bf16_t* g, bf16_t* l) {
  __builtin_amdgcn_global_load_lds(
      (__attribute__((address_space(1))) void*)(void*)g,
      (__attribute__((address_space(3))) void*)l,
      16, 0, 0);
}

// C[m][n] = sum_k A[m][k]*B[n][k]  (A:[M][K], B:[N][K] row-major bf16)
// MODE: 1 scores: flat triangular grid, epilogue mask+exp (no rowsum)
//       2 pv: panel-pinned flat grid, K clamped, rowsum via ones-MFMA, epilogue 1/rs
//       3 fused qkv split; V-third written transposed into Vt
// LDS swizzle: 16B chunk position p of row r holds global chunk p ^ (r&7);
// fragment reads hit all 32 banks 2-way (free, m136). Conflicts measured 0 (R5-R17).
template <int BMv, int BNv, int NW, int MODE, typename OT>
__global__ __launch_bounds__(NW * 64)
void gemm_nt_bf16(const bf16_t* __restrict__ A, const bf16_t* __restrict__ B,
                  OT* __restrict__ C0, OT* __restrict__ C1, OT* __restrict__ C2,
                  int M, int K, int ldc,
                  long strideA, long strideB, long strideC)
{
  constexpr int MW = BMv / 64;       // wave grid: MW x (NW/MW)
  constexpr int RA = BMv / NW;       // rows staged per wave (A)
  constexpr int RB = BNv / NW;       // rows staged per wave (B)

  int bx, by, bz;
  if constexpr (MODE == 1) {
    // Flat XCD-balanced lower-triangle enumeration (S=2048, 128-tiles, 16 panels/batch).
    // XCD x (= blockIdx.x & 7, m09 round-robin) owns panels {x, 15-x} of every batch:
    // weight (x+1) + (16-x) = 17 tiles per batch -> 68 per XCD, exact balance.
    const int f = blockIdx.x;          // 544 blocks
    const int x = f & 7;
    const int j = f >> 3;              // [0, 68)
    bz = j / 17;
    const int r = j % 17;
    by = (r <= x) ? x : 15 - x;
    bx = (r <= x) ? r : r - (x + 1);
  } else if constexpr (MODE == 2) {
    // PV panel-pinned flat grid: 512 blocks. XCD = f&7 owns 8 E row-panels
    // (4 heavy-first pairs; (16-pr)+(pr+1)=17 -> 68 K-units per XCD exactly).
    // bx fastest: the 8 col-blocks of a panel are consecutive ON ONE XCD -> A-panel
    // fetched once, ~2.2 MB/XCD in L2 (R14: 78 MB FETCH with the un-pinned map).
    const int f  = blockIdx.x;
    const int xcd = f & 7;
    const int i  = f >> 3;             // [0,64) within XCD
    bx = i & 7;
    const int p  = i >> 3;             // [0,8) panel slot
    const int j  = p & 3;              // pair index
    const int heavy = (p < 4);         // heavy panels first
    const int g  = xcd * 4 + j;        // [0,32) global (bz,pr) pair
    bz = g >> 3;
    const int pr = g & 7;
    by = heavy ? (15 - pr) : pr;
  } else {
    // XCD-aware remap: pin all x-blocks of an A-panel (y,z) to one XCD.
    // Requires (gridDim.y*gridDim.z) % 8 == 0 -- true here (64).
    const int gx = gridDim.x, gy = gridDim.y;
    const int NP = gy * gridDim.z;
    const int P  = NP >> 3;                         // panels per XCD
    const int flat = blockIdx.x + gx * (blockIdx.y + gy * blockIdx.z);
    const int xcd  = flat & 7;
    const int i    = flat >> 3;
    const int pan  = xcd * P + (i % P);
    bx = i / P;
    by = pan % gy;
    bz = pan / gy;
  }

  const int rowBase = by * BMv;
  const int colBase = bx * BNv;

  __shared__ __align__(16) bf16_t sA[BMv * 64];
  __shared__ __align__(16) bf16_t sB[BNv * 64];

  A += (size_t)bz * strideA;
  B += (size_t)bz * strideB;

  const int tid  = threadIdx.x;
  const int wave = tid >> 6;
  const int lane = tid & 63;
  const int quad = lane >> 4;
  const int ln16 = lane & 15;

  const int wm = (wave % MW) * 64;
  const int wn = (wave / MW) * 64;

  const int rA = lane >> 3;                       // 0..7 row-in-group
  const int sColOff = ((lane & 7) ^ rA) * 8;      // swizzled chunk offset (elems)
  const bf16_t* pA = A + (size_t)(rowBase + wave * RA + rA) * K + sColOff;
  const bf16_t* pB = B + (size_t)(colBase + wave * RB + rA) * K + sColOff;
  bf16_t* ldsA = sA + wave * RA * 64;
  bf16_t* ldsB = sB + wave * RB * 64;

  f32x4 acc[4][4] = {};
  f32x4 acc_rs[4] = {};                           // MODE 2: per-row E sums (ones-MFMA)
  bf16x8 ones;
#pragma unroll
  for (int i = 0; i < 8; i++) ones[i] = (bf16_t)1.0f;

  const int Kend = (MODE == 2) ? (K < rowBase + BMv ? K : rowBase + BMv) : K;

  for (int k0 = 0; k0 < Kend; k0 += 64) {
#pragma unroll
    for (int j = 0; j < RA / 8; j++)
      load_lds16(pA + k0 + (size_t)(8 * j) * K, ldsA + j * 512);
#pragma unroll
    for (int j = 0; j < RB / 8; j++)
      load_lds16(pB + k0 + (size_t)(8 * j) * K, ldsB + j * 512);
    __syncthreads();   // drains vmcnt for all waves

#pragma unroll
    for (int kk = 0; kk < 2; kk++) {
      bf16x8 af[4], bfr[4];
#pragma unroll
      for (int mt = 0; mt < 4; mt++) {
        const int row = wm + mt * 16 + ln16;
        af[mt] = *(const bf16x8*)(sA + row * 64 + (((kk * 4 + quad) ^ (row & 7)) * 8));
      }
#pragma unroll
      for (int nt = 0; nt < 4; nt++) {
        const int row = wn + nt * 16 + ln16;
        bfr[nt] = *(const bf16x8*)(sB + row * 64 + (((kk * 4 + quad) ^ (row & 7)) * 8));
      }
#pragma unroll
      for (int mt = 0; mt < 4; mt++) {
#pragma unroll
        for (int nt = 0; nt < 4; nt++)
          acc[mt][nt] = __builtin_amdgcn_mfma_f32_16x16x32_bf16(af[mt], bfr[nt], acc[mt][nt], 0, 0, 0);
        if constexpr (MODE == 2)
          acc_rs[mt] = __builtin_amdgcn_mfma_f32_16x16x32_bf16(af[mt], ones, acc_rs[mt], 0, 0, 0);
      }
    }
    __syncthreads();
  }

  // epilogue: C/D layout col = lane&15, row = quad*4 + r  [measured m89/m91]
  if constexpr (MODE == 3) {
    const int which = colBase >> 10;               // 128-col tiles never span matrices
    const int cb = colBase & 1023;
    if (which == 2) {
      // V-third: write transposed into Vt[b][e][s]  (b=row>>11, e=col, s=row&2047).
      // Each block covers 128 contiguous s per e-row -> 64B lines fully written
      // within one block/XCD -> L2 write-merge keeps HBM traffic at 33.5 MB.
#pragma unroll
      for (int mt = 0; mt < 4; mt++) {
#pragma unroll
        for (int r = 0; r < 4; r++) {
          const int row = rowBase + wm + mt * 16 + quad * 4 + r;
          const size_t vb = (size_t)(row >> 11) * (1024 * 2048) + (row & 2047);
#pragma unroll
          for (int nt = 0; nt < 4; nt++) {
            const int col = cb + wn + nt * 16 + ln16;
            C2[vb + (size_t)col * 2048] = (OT)acc[mt][nt][r];
          }
        }
      }
    } else {
      OT* Cw = which ? C1 : C0;
#pragma unroll
      for (int mt = 0; mt < 4; mt++) {
#pragma unroll
        for (int r = 0; r < 4; r++) {
          const int row = rowBase + wm + mt * 16 + quad * 4 + r;
#pragma unroll
          for (int nt = 0; nt < 4; nt++) {
            const int col = cb + wn + nt * 16 + ln16;
            Cw[(size_t)row * ldc + col] = (OT)acc[mt][nt][r];
          }
        }
      }
    }
    return;
  }

  OT* Cw = C0 + (size_t)bz * strideC;
#pragma unroll
  for (int mt = 0; mt < 4; mt++) {
#pragma unroll
    for (int r = 0; r < 4; r++) {
      const int row = rowBase + wm + mt * 16 + quad * 4 + r;
      const float rinv = (MODE == 2) ? 1.0f / acc_rs[mt][r] : 1.0f;
#pragma unroll
      for (int nt = 0; nt < 4; nt++) {
        const int col = colBase + wn + nt * 16 + ln16;
        float v = acc[mt][nt][r];
        if constexpr (MODE == 1) {
          v = (col <= row) ? __expf(v * 0.03125f) : 0.0f;   // s/sqrt(1024)
        } else {
          v *= rinv;
        }
        Cw[(size_t)row * ldc + col] = (OT)v;
      }
    }
  }
}

// Fused prep: blocks [0,3072) transpose {Wq,Wk,Wv} fp32 -> bf16 into Wt [3D][D];
// blocks [3072, 7168) convert x fp32 -> bf16 (8 elems/thread, vectorized).
// Disjoint outputs; both consumed by the QKV dispatch that follows on the stream.
__global__ __launch_bounds__(256)
void prep(const float* __restrict__ w0, const float* __restrict__ w1,
          const float* __restrict__ w2, bf16_t* __restrict__ wt, int D,
          const float* __restrict__ x, bf16_t* __restrict__ xb, long n)
{
  const int b = blockIdx.x;
  const int tid = threadIdx.x;
  __shared__ float tile[32][33];
  if (b < 3072) {
    const int z  = b >> 10;                        // 0..2 selects W matrix
    const int xy = b & 1023;
    const int c0 = (xy & 31) * 32, r0 = (xy >> 5) * 32;
    const int tx = tid & 31, ty = tid >> 5;        // (32, 8)
    const float* in = (z == 0) ? w0 : (z == 1) ? w1 : w2;
    bf16_t* o = wt + (size_t)z * D * D;
#pragma unroll
    for (int i = 0; i < 32; i += 8)
      tile[ty + i][tx] = in[(size_t)(r0 + ty + i) * D + (c0 + tx)];
    __syncthreads();
#pragma unroll
    for (int i = 0; i < 32; i += 8)
      o[(size_t)(c0 + ty + i) * D + (r0 + tx)] = (bf16_t)tile[tx][ty + i];
  } else {
    const long i = ((long)(b - 3072) * 256 + tid) * 8;
    if (i + 7 < n) {
      float4 a = *(const float4*)(x + i);
      float4 c = *(const float4*)(x + i + 4);
      bf16x8 o;
      o[0] = (bf16_t)a.x; o[1] = (bf16_t)a.y; o[2] = (bf16_t)a.z; o[3] = (bf16_t)a.w;
      o[4] = (bf16_t)c.x; o[5] = (bf16_t)c.y; o[6] = (bf16_t)c.z; o[7] = (bf16_t)c.w;
      *(bf16x8*)(xb + i) = o;
    }
  }
}

extern "C" void kernel_launch(void* const* d_in, const int* in_sizes, int n_in,
                              void* d_out, int out_size, void* d_ws, size_t ws_size,
                              hipStream_t stream) {
  const float* x  = (const float*)d_in[0];
  const float* Wq = (const float*)d_in[1];
  const float* Wk = (const float*)d_in[2];
  const float* Wv = (const float*)d_in[3];
  float* out = (float*)d_out;

  const int Bb = 4, S = 2048, D = 1024;
  const int M = Bb * S;  // 8192

  // ws (bf16 elems): Q | K | Vt | Wt(3*D*D) | Xb | (tail)   = 90,177,536 B (fits)
  // Sc (Bb*S*S == 2*M*D) aliases [Xb | tail].
  bf16_t* ws = (bf16_t*)d_ws;
  bf16_t* Q   = ws;
  bf16_t* Kp  = Q  + (size_t)M * D;
  bf16_t* Vt  = Kp + (size_t)M * D;
  bf16_t* Wt  = Vt + (size_t)M * D;          // [3072][1024] stacked
  bf16_t* Xb  = Wt + 3 * (size_t)D * D;
  bf16_t* Sc  = Xb;

  // 1) prep: W transpose+cvt (3072 blocks) || x cvt (4096 blocks)
  prep<<<dim3(3072 + 4096), dim3(256), 0, stream>>>(Wq, Wk, Wv, Wt, D, x, Xb, (long)M * D);

  // 2) fused projections: {Q,K,Vt} = Xb * Wt^T  (V written transposed directly)
  gemm_nt_bf16<128, 128, 4, 3, bf16_t><<<dim3(3 * D / 128, M / 128, 1), dim3(256), 0, stream>>>(
      Xb, Wt, Q, Kp, Vt, M, D, D, 0, 0, 0);

  // 3) E = masked-exp(Q*K^T/32)  (flat triangular grid: 544 tiles, 68/XCD exact)
  gemm_nt_bf16<128, 128, 4, 1, bf16_t><<<dim3(544, 1, 1), dim3(256), 0, stream>>>(
      Q, Kp, Sc, Sc, Sc, S, D, S, (long)S * D, (long)S * D, (long)S * S);

  // 4) out = (E*V) / (E*ones)  (panel-pinned flat grid: 512 blocks, 68 K-units/XCD)
  gemm_nt_bf16<128, 128, 4, 2, float><<<dim3(512, 1, 1), dim3(256), 0, stream>>>(
      Sc, Vt, out, out, out, S, S, D, (long)S * S, (long)D * S, (long)S * D);
}